// Round 8
// baseline (93.567 us; speedup 1.0000x reference)
//
#include <hip/hip_runtime.h>

#define D 512
#define C 256
#define B 512
#define NS 8192
#define MAGIC1 0x13572468u
#define MAGIC2 0x2468ACE1u

__device__ __forceinline__ float wave_sum(float v) {
#pragma unroll
    for (int off = 32; off > 0; off >>= 1) v += __shfl_xor(v, off, 64);
    return v;
}
__device__ __forceinline__ float wave_max(float v) {
#pragma unroll
    for (int off = 32; off > 0; off >>= 1) v = fmaxf(v, __shfl_xor(v, off, 64));
    return v;
}
// full 512-thread (8-wave) reduction, 2 barriers
__device__ __forceinline__ float block_sum8(float v, float* sm) {
    v = wave_sum(v);
    int tid = threadIdx.x;
    if ((tid & 63) == 0) sm[tid >> 6] = v;
    __syncthreads();
    float r = ((sm[0] + sm[1]) + (sm[2] + sm[3])) + ((sm[4] + sm[5]) + (sm[6] + sm[7]));
    __syncthreads();
    return r;
}
// per-half (4-wave) reductions: threads 0-255 / 256-511 independent
__device__ __forceinline__ float half_sum(float v, float* sm) {
    v = wave_sum(v);
    int tid = threadIdx.x;
    if ((tid & 63) == 0) sm[tid >> 6] = v;
    __syncthreads();
    int base = (tid >> 8) << 2;
    float r = (sm[base] + sm[base + 1]) + (sm[base + 2] + sm[base + 3]);
    __syncthreads();
    return r;
}
__device__ __forceinline__ float half_max(float v, float* sm) {
    v = wave_max(v);
    int tid = threadIdx.x;
    if ((tid & 63) == 0) sm[tid >> 6] = v;
    __syncthreads();
    int base = (tid >> 8) << 2;
    float r = fmaxf(fmaxf(sm[base], sm[base + 1]), fmaxf(sm[base + 2], sm[base + 3]));
    __syncthreads();
    return r;
}

// ---- single fused kernel: 256 blocks x 512 threads, software grid barrier ----
// Grid of exactly 256 blocks on 256 CUs: every block is resident (1 block/CU
// worst case), so spin-wait barriers cannot deadlock.
__global__ __launch_bounds__(512) void fused_kernel(
        const float* __restrict__ xq, const int* __restrict__ yq,
        const float* __restrict__ xs, const int* __restrict__ ys,
        const int* __restrict__ pos, unsigned short* __restrict__ musT,
        float* __restrict__ counts, float* __restrict__ nm,
        float* __restrict__ qcount, float* __restrict__ d2sum,
        float* __restrict__ loss_b, unsigned int* __restrict__ flag1,
        unsigned int* __restrict__ flag2, float* __restrict__ out) {
    __shared__ unsigned short list[NS];          // 16 KB
    __shared__ int cnt;
    __shared__ float sm[8];
    __shared__ __align__(16) float part4[4][D];  // 8 KB
    __shared__ float part[2][8][C];              // 16 KB
    __shared__ float sh_t[2];

    int bid = blockIdx.x, tid = threadIdx.x;
    int c = bid;

    // ================= Phase A1: prototype for class c =================
    if (tid == 0) cnt = 0;
    __syncthreads();
    for (int i = tid; i < NS; i += 512)
        if (ys[i] == c) { int p = atomicAdd(&cnt, 1); list[p] = (unsigned short)i; }
    __syncthreads();
    int n = cnt;
    {
        int q = tid >> 7, l = tid & 127;  // quarter-group q handles rows j%4==q
        float4 acc = make_float4(0.f, 0.f, 0.f, 0.f);
        for (int base = 0; base < n; base += 32) {
            float4 mv[8];
            float w[8];
#pragma unroll
            for (int k = 0; k < 8; ++k) {
                int jj = base + (k << 2) + q;
                int cj = jj < n ? jj : (n > 0 ? n - 1 : 0);
                int row = list[cj];
                mv[k] = *(const float4*)(xs + (size_t)row * D + (l << 2));
                w[k] = (jj < n) ? 1.f : 0.f;
            }
#pragma unroll
            for (int k = 0; k < 8; ++k) {
                acc.x = fmaf(mv[k].x, w[k], acc.x);
                acc.y = fmaf(mv[k].y, w[k], acc.y);
                acc.z = fmaf(mv[k].z, w[k], acc.z);
                acc.w = fmaf(mv[k].w, w[k], acc.w);
            }
        }
        *(float4*)&part4[q][l << 2] = acc;
    }
    __syncthreads();
    float m = (part4[0][tid] + part4[1][tid]) + (part4[2][tid] + part4[3][tid]);
    if (n == 0) m = 0.f;
    unsigned int u = __float_as_uint(m);
    u += 0x7fffu + ((u >> 16) & 1u);
    musT[(size_t)tid * C + c] = (unsigned short)(u >> 16);  // bf16 RNE, transposed
    float s = block_sum8(m * m, sm);
    if (tid == 0) { nm[c] = s; counts[c] = (float)n; }

    // ================= Phase A2: query stats for class c =================
    __syncthreads();
    if (tid == 0) cnt = 0;
    __syncthreads();
    if (yq[tid] == c) { int p = atomicAdd(&cnt, 1); list[p] = (unsigned short)tid; }
    __syncthreads();
    int nq_ = cnt;
    float ssum = 0.f, sq = 0.f;
    for (int j = 0; j < nq_; ++j) {
        int row = list[j];
        float v = xq[(size_t)row * D + tid];
        ssum += v;
        sq = fmaf(v, v, sq);
    }
    float nrm = block_sum8(ssum * ssum, sm);
    float tsq = block_sum8(sq, sm);
    if (tid == 0) {
        qcount[c] = (float)nq_;
        d2sum[c] = (nq_ > 0) ? (tsq - nrm / (float)nq_) : 0.f;
    }

    // ---- publish phase A: device fence + release flag ----
    __threadfence();
    __syncthreads();
    if (tid == 0)
        __hip_atomic_store(&flag1[c], MAGIC1, __ATOMIC_RELEASE, __HIP_MEMORY_SCOPE_AGENT);

    // ---- wait for all classes (acquire; stale-skip on replays is value-identical) ----
    if (tid < C) {
        while (__hip_atomic_load(&flag1[tid], __ATOMIC_ACQUIRE, __HIP_MEMORY_SCOPE_AGENT) != MAGIC1)
            __builtin_amdgcn_s_sleep(1);
    }
    __syncthreads();

    // ================= Phase B: 2 query rows per block =================
    int b0 = bid * 2;
    int lane = tid & 63;
    int ks = tid >> 6;        // wave id = K slice
    int dbase = ks << 6;
    int cbase = lane << 2;    // 4 classes per lane

    float xr0 = xq[(size_t)(b0 + 0) * D + dbase + lane];
    float xr1 = xq[(size_t)(b0 + 1) * D + dbase + lane];
    float nq0 = block_sum8(xr0 * xr0, sm);
    float nq1 = block_sum8(xr1 * xr1, sm);

    const unsigned short* mtb = musT + (size_t)dbase * C + cbase;
    float4 a0 = make_float4(0.f, 0.f, 0.f, 0.f);
    float4 a1 = make_float4(0.f, 0.f, 0.f, 0.f);
#pragma unroll
    for (int j0 = 0; j0 < 64; j0 += 8) {
        uint2 mv[8];
#pragma unroll
        for (int k = 0; k < 8; ++k)
            mv[k] = *(const uint2*)(mtb + (size_t)(j0 + k) * C);
#pragma unroll
        for (int k = 0; k < 8; ++k) {
            float x0 = __int_as_float(__builtin_amdgcn_readlane(__float_as_int(xr0), j0 + k));
            float x1 = __int_as_float(__builtin_amdgcn_readlane(__float_as_int(xr1), j0 + k));
            float c0 = __uint_as_float(mv[k].x << 16);
            float c1 = __uint_as_float(mv[k].x & 0xffff0000u);
            float c2 = __uint_as_float(mv[k].y << 16);
            float c3 = __uint_as_float(mv[k].y & 0xffff0000u);
            a0.x = fmaf(c0, x0, a0.x); a0.y = fmaf(c1, x0, a0.y);
            a0.z = fmaf(c2, x0, a0.z); a0.w = fmaf(c3, x0, a0.w);
            a1.x = fmaf(c0, x1, a1.x); a1.y = fmaf(c1, x1, a1.y);
            a1.z = fmaf(c2, x1, a1.z); a1.w = fmaf(c3, x1, a1.w);
        }
    }
    *(float4*)&part[0][ks][cbase] = a0;
    *(float4*)&part[1][ks][cbase] = a1;
    __syncthreads();

    // threads 0-255 -> row 0, threads 256-511 -> row 1
    int h = tid >> 8;
    int cc_ = tid & (C - 1);
    int b = b0 + h;
    float g = 0.f;
#pragma unroll
    for (int k = 0; k < 8; ++k) g += part[h][k][cc_];

    int t = ys[pos[b]];
    float nqv = h ? nq1 : nq0;
    float count = counts[cc_], nmv = nm[cc_];
    float Cn = count, dt = g, m2 = nmv;
    if (cc_ == t) { Cn -= 1.0f; dt = g - nqv; m2 = nmv - 2.0f * g + nqv; }
    float den = fmaxf(Cn, 0.1f);
    float inv = 1.0f / den;
    float dist2 = nqv - 2.0f * dt * inv + m2 * inv * inv;
    float logit = (Cn > 0.1f) ? (-0.5f * dist2) : 0.0f;
    if (cc_ == t) sh_t[h] = logit;  // visible after half_max's barrier

    float mx = half_max(logit, sm);
    float e = expf(logit - mx);
    float se = half_sum(e, sm);
    if (cc_ == 0) loss_b[b] = -(sh_t[h] - mx - logf(se));

    // ---- publish phase B ----
    __threadfence();
    __syncthreads();
    if (tid == 0)
        __hip_atomic_store(&flag2[bid], MAGIC2, __ATOMIC_RELEASE, __HIP_MEMORY_SCOPE_AGENT);

    // ================= block 0: final reduction =================
    if (bid == 0) {
        if (tid < C) {
            while (__hip_atomic_load(&flag2[tid], __ATOMIC_ACQUIRE, __HIP_MEMORY_SCOPE_AGENT) != MAGIC2)
                __builtin_amdgcn_s_sleep(1);
        }
        __syncthreads();
        float lsum = block_sum8(loss_b[tid], sm);  // 512 rows, one per thread
        float cv = (tid < C) ? qcount[tid] : 0.f;
        float dv = (tid < C) ? d2sum[tid] : 0.f;
        bool valid = cv >= 3.0f;  // MIN_SAMPLES
        float tot = block_sum8(valid ? dv : 0.f, sm);
        float ctot = block_sum8(valid ? cv : 0.f, sm);
        if (tid == 0) {
            out[0] = lsum / (float)B;
            out[1] = (ctot > 0.f) ? tot / fmaxf(ctot, 1.0f) : 0.0f;
        }
    }
}

extern "C" void kernel_launch(void* const* d_in, const int* in_sizes, int n_in,
                              void* d_out, int out_size, void* d_ws, size_t ws_size,
                              hipStream_t stream) {
    const float* xq = (const float*)d_in[0];
    const int* yq = (const int*)d_in[1];
    const float* xs = (const float*)d_in[2];
    const int* ys = (const int*)d_in[3];
    const int* pos = (const int*)d_in[4];
    float* out = (float*)d_out;

    float* wsf = (float*)d_ws;
    unsigned short* musT = (unsigned short*)d_ws;  // D*C bf16 = 256 KB = 65536 f32 slots
    float* counts = wsf + 65536;                   // 256
    float* nm = wsf + 65792;                       // 256
    float* qcount = wsf + 66048;                   // 256
    float* d2sum = wsf + 66304;                    // 256
    float* loss_b = wsf + 66560;                   // 512
    unsigned int* flag1 = (unsigned int*)(wsf + 67072);  // 256
    unsigned int* flag2 = (unsigned int*)(wsf + 67328);  // 256

    fused_kernel<<<C, 512, 0, stream>>>(xq, yq, xs, ys, pos, musT, counts, nm,
                                        qcount, d2sum, loss_b, flag1, flag2, out);
}

// Round 9
// 24.849 us; speedup vs baseline: 3.7653x; 3.7653x over previous
//
#include <hip/hip_runtime.h>

#define D 512
#define C 256
#define B 512
#define NS 8192

__device__ __forceinline__ float wave_sum(float v) {
#pragma unroll
    for (int off = 32; off > 0; off >>= 1) v += __shfl_xor(v, off, 64);
    return v;
}
__device__ __forceinline__ float wave_max(float v) {
#pragma unroll
    for (int off = 32; off > 0; off >>= 1) v = fmaxf(v, __shfl_xor(v, off, 64));
    return v;
}
// full 512-thread (8-wave) reduction, 2 barriers
__device__ __forceinline__ float block_sum8(float v, float* sm) {
    v = wave_sum(v);
    int tid = threadIdx.x;
    if ((tid & 63) == 0) sm[tid >> 6] = v;
    __syncthreads();
    float r = ((sm[0] + sm[1]) + (sm[2] + sm[3])) + ((sm[4] + sm[5]) + (sm[6] + sm[7]));
    __syncthreads();
    return r;
}
// per-half (4-wave) reductions: threads 0-255 / 256-511 independent
__device__ __forceinline__ float half_sum(float v, float* sm) {
    v = wave_sum(v);
    int tid = threadIdx.x;
    if ((tid & 63) == 0) sm[tid >> 6] = v;
    __syncthreads();
    int base = (tid >> 8) << 2;
    float r = (sm[base] + sm[base + 1]) + (sm[base + 2] + sm[base + 3]);
    __syncthreads();
    return r;
}
__device__ __forceinline__ float half_max(float v, float* sm) {
    v = wave_max(v);
    int tid = threadIdx.x;
    if ((tid & 63) == 0) sm[tid >> 6] = v;
    __syncthreads();
    int base = (tid >> 8) << 2;
    float r = fmaxf(fmaxf(sm[base], sm[base + 1]), fmaxf(sm[base + 2], sm[base + 3]));
    __syncthreads();
    return r;
}

// ---- K1: blocks [0,C) = class prototypes (bf16 transposed store);
//          blocks [C,2C) = query class stats ----
__global__ __launch_bounds__(512) void stats_kernel(
        const float* __restrict__ xq, const int* __restrict__ yq,
        const float* __restrict__ xs, const int* __restrict__ ys,
        unsigned short* __restrict__ musT, float* __restrict__ counts,
        float* __restrict__ nm, float* __restrict__ qcount,
        float* __restrict__ d2sum, float* __restrict__ out) {
    __shared__ unsigned short list[NS];           // 16 KB
    __shared__ int cnt;
    __shared__ float sm[8];
    __shared__ __align__(16) float part4[4][D];   // 8 KB
    int bid = blockIdx.x, tid = threadIdx.x;

    if (bid < C) {
        int c = bid;
        if (tid == 0) cnt = 0;
        __syncthreads();
        for (int i = tid; i < NS; i += 512)
            if (ys[i] == c) { int p = atomicAdd(&cnt, 1); list[p] = (unsigned short)i; }
        __syncthreads();
        int n = cnt;
        int q = tid >> 7, l = tid & 127;          // quarter-group q handles rows j%4==q
        float4 acc = make_float4(0.f, 0.f, 0.f, 0.f);
        for (int base = 0; base < n; base += 32) {
            float4 mv[8];
            float w[8];
#pragma unroll
            for (int k = 0; k < 8; ++k) {
                int jj = base + (k << 2) + q;
                int cj = jj < n ? jj : n - 1;
                int row = list[cj];
                mv[k] = *(const float4*)(xs + (size_t)row * D + (l << 2));  // 16B coalesced
                w[k] = (jj < n) ? 1.f : 0.f;
            }
#pragma unroll
            for (int k = 0; k < 8; ++k) {
                acc.x = fmaf(mv[k].x, w[k], acc.x);
                acc.y = fmaf(mv[k].y, w[k], acc.y);
                acc.z = fmaf(mv[k].z, w[k], acc.z);
                acc.w = fmaf(mv[k].w, w[k], acc.w);
            }
        }
        *(float4*)&part4[q][l << 2] = acc;
        __syncthreads();
        float m = (part4[0][tid] + part4[1][tid]) + (part4[2][tid] + part4[3][tid]);
        // bf16 RNE store, transposed
        unsigned int u = __float_as_uint(m);
        u += 0x7fffu + ((u >> 16) & 1u);
        musT[(size_t)tid * C + c] = (unsigned short)(u >> 16);
        float s = block_sum8(m * m, sm);   // nm from exact f32 prototype
        if (tid == 0) { nm[c] = s; counts[c] = (float)n; }
    } else {
        int c = bid - C;
        if (tid == 0) cnt = 0;
        __syncthreads();
        if (yq[tid] == c) { int p = atomicAdd(&cnt, 1); list[p] = (unsigned short)tid; }
        __syncthreads();
        int n = cnt;
        float ssum = 0.f, sq = 0.f;
        for (int j0 = 0; j0 < n; j0 += 4) {   // 4-deep clamped: no serial remainder
            float v[4], w[4];
#pragma unroll
            for (int k = 0; k < 4; ++k) {
                int jj = j0 + k;
                int row = list[jj < n ? jj : n - 1];
                v[k] = xq[(size_t)row * D + tid];
                w[k] = (jj < n) ? 1.f : 0.f;
            }
#pragma unroll
            for (int k = 0; k < 4; ++k) {
                float vw = v[k] * w[k];
                ssum += vw;
                sq = fmaf(vw, v[k], sq);
            }
        }
        float nrm = block_sum8(ssum * ssum, sm);
        float tsq = block_sum8(sq, sm);
        if (tid == 0) {
            qcount[c] = (float)n;
            d2sum[c] = (n > 0) ? (tsq - nrm / (float)n) : 0.f;
            if (c == 0) out[0] = 0.f;  // loss accumulator, stream-ordered before K2
        }
    }
}

// ---- K2: 256 blocks x 512 threads, 2 query rows/block; bf16 musT, row norms computed here ----
__global__ __launch_bounds__(512) void loss_kernel(
        const float* __restrict__ xq, const int* __restrict__ ys,
        const int* __restrict__ pos, const unsigned short* __restrict__ musT,
        const float* __restrict__ nm, const float* __restrict__ cc,
        const float* __restrict__ qcount, const float* __restrict__ d2sum,
        float* __restrict__ out) {
    __shared__ float part[2][8][C];  // 16 KB K-slice partials
    __shared__ float sm[8];
    __shared__ float sh_t[2];
    int tid = threadIdx.x;
    int b0 = blockIdx.x * 2;
    int lane = tid & 63;
    int ks = tid >> 6;            // wave id = K slice
    int dbase = ks << 6;
    int cbase = lane << 2;        // 4 classes per lane

    // full rows live across the block's registers: wave ks, lane l -> dim dbase+l
    float xr0 = xq[(size_t)(b0 + 0) * D + dbase + lane];
    float xr1 = xq[(size_t)(b0 + 1) * D + dbase + lane];
    float nq0 = block_sum8(xr0 * xr0, sm);
    float nq1 = block_sum8(xr1 * xr1, sm);

    const unsigned short* mtb = musT + (size_t)dbase * C + cbase;
    float4 a0 = make_float4(0.f, 0.f, 0.f, 0.f);
    float4 a1 = make_float4(0.f, 0.f, 0.f, 0.f);
#pragma unroll
    for (int j0 = 0; j0 < 64; j0 += 8) {
        uint2 mv[8];
#pragma unroll
        for (int k = 0; k < 8; ++k)
            mv[k] = *(const uint2*)(mtb + (size_t)(j0 + k) * C);  // 512B/wave-instr, coalesced
#pragma unroll
        for (int k = 0; k < 8; ++k) {
            float x0 = __int_as_float(__builtin_amdgcn_readlane(__float_as_int(xr0), j0 + k));
            float x1 = __int_as_float(__builtin_amdgcn_readlane(__float_as_int(xr1), j0 + k));
            float c0 = __uint_as_float(mv[k].x << 16);
            float c1 = __uint_as_float(mv[k].x & 0xffff0000u);
            float c2 = __uint_as_float(mv[k].y << 16);
            float c3 = __uint_as_float(mv[k].y & 0xffff0000u);
            a0.x = fmaf(c0, x0, a0.x); a0.y = fmaf(c1, x0, a0.y);
            a0.z = fmaf(c2, x0, a0.z); a0.w = fmaf(c3, x0, a0.w);
            a1.x = fmaf(c0, x1, a1.x); a1.y = fmaf(c1, x1, a1.y);
            a1.z = fmaf(c2, x1, a1.z); a1.w = fmaf(c3, x1, a1.w);
        }
    }
    *(float4*)&part[0][ks][cbase] = a0;
    *(float4*)&part[1][ks][cbase] = a1;
    __syncthreads();

    // threads 0-255 -> row 0, threads 256-511 -> row 1 (concurrent softmaxes)
    int h = tid >> 8;
    int c = tid & (C - 1);
    int b = b0 + h;
    float g = 0.f;
#pragma unroll
    for (int k = 0; k < 8; ++k) g += part[h][k][c];

    int t = ys[pos[b]];
    float nqv = h ? nq1 : nq0;
    float count = cc[c], nmv = nm[c];
    float Cn = count, dt = g, m2 = nmv;
    if (c == t) { Cn -= 1.0f; dt = g - nqv; m2 = nmv - 2.0f * g + nqv; }
    float den = fmaxf(Cn, 0.1f);
    float inv = 1.0f / den;
    float dist2 = nqv - 2.0f * dt * inv + m2 * inv * inv;
    float logit = (Cn > 0.1f) ? (-0.5f * dist2) : 0.0f;
    if (c == t) sh_t[h] = logit;  // visible after half_max's barrier

    float mx = half_max(logit, sm);
    float e = expf(logit - mx);
    float se = half_sum(e, sm);
    if (c == 0) atomicAdd(out, -(sh_t[h] - mx - logf(se)) * (1.0f / (float)B));

    if (blockIdx.x == 0) {  // var_intra epilogue
        float cv = (tid < C) ? qcount[tid] : 0.f;
        float dv = (tid < C) ? d2sum[tid] : 0.f;
        bool valid = cv >= 3.0f;  // MIN_SAMPLES
        float tot = block_sum8(valid ? dv : 0.f, sm);
        float ctot = block_sum8(valid ? cv : 0.f, sm);
        if (tid == 0) out[1] = (ctot > 0.f) ? tot / fmaxf(ctot, 1.0f) : 0.0f;
    }
}

extern "C" void kernel_launch(void* const* d_in, const int* in_sizes, int n_in,
                              void* d_out, int out_size, void* d_ws, size_t ws_size,
                              hipStream_t stream) {
    const float* xq = (const float*)d_in[0];
    const int* yq = (const int*)d_in[1];
    const float* xs = (const float*)d_in[2];
    const int* ys = (const int*)d_in[3];
    const int* pos = (const int*)d_in[4];
    float* out = (float*)d_out;

    float* wsf = (float*)d_ws;
    unsigned short* musT = (unsigned short*)d_ws;  // D*C bf16 = 256 KB = 65536 f32 slots
    float* counts = wsf + 65536;   // 256
    float* nm = wsf + 65792;       // 256
    float* qcount = wsf + 66048;   // 256
    float* d2sum = wsf + 66304;    // 256
    // every slot fully overwritten each launch -> no memset needed

    stats_kernel<<<2 * C, 512, 0, stream>>>(xq, yq, xs, ys, musT, counts, nm,
                                            qcount, d2sum, out);
    loss_kernel<<<C, 512, 0, stream>>>(xq, ys, pos, musT, nm, counts,
                                       qcount, d2sum, out);
}